// Round 17
// baseline (312.536 us; speedup 1.0000x reference)
//
#include <hip/hip_runtime.h>
#include <hip/hip_bf16.h>

// AAE_GCN round 17:
//  1) fmg_enc1: splitK 25 -> 63 z-slices (1008 blocks, ~4/CU; was 1.56 waves/SIMD).
//  2) fmg_dec3: explicit 1-step fragment prefetch (named regs).
//  3) spmm: paired uint2 index reads from LDS.
//  Else identical to r16.

#define LRELU(v) ((v) > 0.f ? (v) : 0.01f * (v))

static constexpr int Bb = 512;
static constexpr int Nn = 20000;
static constexpr int Ee = 640000;
static constexpr int KBn = 2500;
static constexpr int NPD = 20096;

typedef __attribute__((ext_vector_type(8))) short short8;
typedef __attribute__((ext_vector_type(4))) float f32x4;

__device__ __forceinline__ ushort f2bf(float f) {
  uint u = __builtin_bit_cast(uint, f);
  u = u + 0x7FFFu + ((u >> 16) & 1u);  // RTNE
  return (ushort)(u >> 16);
}
__device__ __forceinline__ float bfLo(uint u) {
  return __builtin_bit_cast(float, u << 16);
}
__device__ __forceinline__ float bfHi(uint u) {
  return __builtin_bit_cast(float, u & 0xffff0000u);
}

// ---------- transpose + noise + dinv-fold -> xs chunks [4][Nn][128] bf16 ----------
__global__ void transpose_xs_k(const float* __restrict__ a, const float* __restrict__ nz,
                               const float* __restrict__ dinv, ushort* __restrict__ xs) {
  __shared__ ushort tile[64][65];
  int c0 = blockIdx.x * 64;
  int p = blockIdx.y;
  int chunk = p >> 1;
  int sub = (p & 1) * 64;
  int rbase = p * 64;
  for (int i = threadIdx.x; i < 64 * 64; i += 256) {
    int rr = i >> 6, cc = i & 63;
    int r = rbase + rr, c = c0 + cc;
    ushort v = 0;
    if (c < Nn) {
      size_t idx = (size_t)r * Nn + c;
      v = f2bf(dinv[c] * (a[idx] + 0.1f * nz[idx]));
    }
    tile[rr][cc] = v;
  }
  __syncthreads();
  for (int i = threadIdx.x; i < 64 * 64; i += 256) {
    int cc = i >> 6, rr = i & 63;
    int c = c0 + cc;
    if (c < Nn) xs[(size_t)chunk * Nn * 128 + (size_t)c * 128 + sub + rr] = tile[rr][cc];
  }
}

// ---------- degree histogram + range check ----------
__global__ void hist_check_k(const int* __restrict__ src, const int* __restrict__ dst, int E,
                             int* __restrict__ cnt, int* __restrict__ flag) {
  int i = blockIdx.x * 256 + threadIdx.x;
  if (i < E) {
    int s = src[i], d = dst[i];
    if ((unsigned)s >= (unsigned)Nn || (unsigned)d >= (unsigned)Nn) {
      atomicExch(flag, 1);
    } else {
      atomicAdd(&cnt[d], 1);
    }
  }
}

// ---------- offsets via wave prefix + atomic bump ----------
__global__ void offs_k(const int* __restrict__ cnt, int* __restrict__ offs,
                       int* __restrict__ cursor, float* __restrict__ dinv,
                       int* __restrict__ bump) {
  int i = blockIdx.x * 256 + threadIdx.x;
  int l = threadIdx.x & 63;
  int v = (i < Nn) ? cnt[i] : 0;
  int x = v;
#pragma unroll
  for (int d = 1; d < 64; d <<= 1) {
    int t = __shfl_up(x, d);
    if (l >= d) x += t;
  }
  int total = __shfl(x, 63);
  int base = 0;
  if (l == 0) base = atomicAdd(bump, total);
  base = __shfl(base, 0);
  int excl = base + x - v;
  if (i < Nn) {
    offs[i] = excl;
    cursor[i] = excl;
    dinv[i] = rsqrtf(2.0f + (float)v);
  }
}

// ---------- scatter edges (byte offsets of 256B chunk rows) ----------
__global__ void scatter_k(const int* __restrict__ src, const int* __restrict__ dst, int E,
                          int* __restrict__ cursor, uint* __restrict__ eOff) {
  int i = blockIdx.x * 256 + threadIdx.x;
  if (i < E) {
    int s = src[i], d = dst[i];
    if ((unsigned)s >= (unsigned)Nn || (unsigned)d >= (unsigned)Nn) return;
    int p = atomicAdd(&cursor[d], 1);
    eOff[p] = (uint)s * 256u;
  }
}

// ---------- SpMM fm output, 16-deep gathers + paired index reads ----------
__global__ __launch_bounds__(256) void spmm_fm_k(
    const ushort* __restrict__ xs, const uint* __restrict__ eOff, const int* __restrict__ offs,
    const int* __restrict__ cnt, const float* __restrict__ dinv, const float* __restrict__ wg,
    const float* __restrict__ bg, ushort* __restrict__ gfm) {
  __shared__ uint sIdx[4][64];
  __shared__ ushort sOut[128][8];
  int bid = blockIdx.x;
  int chunk = bid & 3;
  int grp = bid >> 2;
  int wv = threadIdx.x >> 6, l = threadIdx.x & 63;
  const char* base = (const char*)(xs + (size_t)chunk * Nn * 128) + l * 4;
  float wgv = wg[0], bb = bg[0];

#pragma unroll
  for (int sub = 0; sub < 2; ++sub) {
    int n = grp * 8 + wv * 2 + sub;
    int o = offs[n], c = cnt[n];
    const uint* ep = eOff + o;
    uint su = *(const uint*)(base + (size_t)n * 256);
    float a00 = 2.0f * bfLo(su), a01 = 2.0f * bfHi(su);
    float a10 = 0.f, a11 = 0.f;

    for (int bi = 0; bi < c; bi += 64) {
      int rem = c - bi;
      if (rem > 64) rem = 64;
      sIdx[wv][l] = (l < rem) ? ep[bi + l] : 0u;
      int i = 0;
      for (; i + 16 <= rem; i += 16) {
        uint u[16];
#pragma unroll
        for (int j = 0; j < 8; ++j) {
          uint2 pr = *(const uint2*)&sIdx[wv][i + 2 * j];
          u[2 * j] = pr.x;
          u[2 * j + 1] = pr.y;
        }
        uint g[16];
#pragma unroll
        for (int j = 0; j < 16; ++j) g[j] = *(const uint*)(base + u[j]);
#pragma unroll
        for (int j = 0; j < 16; j += 2) {
          a00 += bfLo(g[j]);
          a01 += bfHi(g[j]);
          a10 += bfLo(g[j + 1]);
          a11 += bfHi(g[j + 1]);
        }
      }
      for (; i + 4 <= rem; i += 4) {
        uint2 p0 = *(const uint2*)&sIdx[wv][i];
        uint2 p1 = *(const uint2*)&sIdx[wv][i + 2];
        uint g0 = *(const uint*)(base + p0.x);
        uint g1 = *(const uint*)(base + p0.y);
        uint g2 = *(const uint*)(base + p1.x);
        uint g3 = *(const uint*)(base + p1.y);
        a00 += bfLo(g0);
        a01 += bfHi(g0);
        a10 += bfLo(g1);
        a11 += bfHi(g1);
        a00 += bfLo(g2);
        a01 += bfHi(g2);
        a10 += bfLo(g3);
        a11 += bfHi(g3);
      }
      for (; i < rem; ++i) {
        uint u = *(const uint*)(base + sIdx[wv][i]);
        a00 += bfLo(u);
        a01 += bfHi(u);
      }
    }

    float wdn = wgv * dinv[n];
    float v0 = wdn * (a00 + a10) + bb;
    float v1 = wdn * (a01 + a11) + bb;
    v0 = LRELU(v0);
    v1 = LRELU(v1);
    int j = wv * 2 + sub;
    sOut[2 * l][j] = f2bf(v0);
    sOut[2 * l + 1][j] = f2bf(v1);
  }
  __syncthreads();
  int row = threadIdx.x >> 1, half = threadIdx.x & 1;
  uint2 v = *(const uint2*)&sOut[row][half * 4];
  int m = chunk * 128 + row;
  *(uint2*)&gfm[((size_t)grp * 512 + m) * 8 + half * 4] = v;
}

// ---------- enc1_w -> bf16 fragment-major ----------
__global__ void conv_we_k(const float* __restrict__ W, ushort* __restrict__ wef) {
  int n = blockIdx.x * 256 + threadIdx.x;
  int kb = blockIdx.y;
  ushort v[8];
#pragma unroll
  for (int j = 0; j < 8; ++j) v[j] = f2bf(W[(size_t)(8 * kb + j) * 512 + n]);
  uint4 pk;
  pk.x = (uint)v[0] | ((uint)v[1] << 16);
  pk.y = (uint)v[2] | ((uint)v[3] << 16);
  pk.z = (uint)v[4] | ((uint)v[5] << 16);
  pk.w = (uint)v[6] | ((uint)v[7] << 16);
  *(uint4*)&wef[((size_t)kb * 512 + n) * 8] = pk;
}

// ---------- enc1 fragment-major GEMM, splitK 63 x 10 K-steps ----------
__global__ __launch_bounds__(256) void fmg_enc1_k(const ushort* __restrict__ gfm,
                                                  const ushort* __restrict__ wef,
                                                  float* __restrict__ C) {
  int n0 = blockIdx.x * 128, m0 = blockIdx.y * 128;
  int l = threadIdx.x & 63, w = threadIdx.x >> 6;
  int wr = w >> 1, wc = w & 1;
  int lrow = l & 15, lkg = l >> 4;
  f32x4 acc[4][4] = {};
  int ksBeg = blockIdx.z * 10;
  int ksEnd = ksBeg + 10;
  if (ksEnd > 625) ksEnd = 625;

  for (int ks = ksBeg; ks < ksEnd; ++ks) {
    int kb = ks * 4 + lkg;
    short8 a[4], b[4];
#pragma unroll
    for (int mi = 0; mi < 4; ++mi) {
      int m = m0 + wr * 64 + mi * 16 + lrow;
      a[mi] = *(const short8*)&gfm[((size_t)kb * 512 + m) * 8];
    }
#pragma unroll
    for (int nj = 0; nj < 4; ++nj) {
      int n = n0 + wc * 64 + nj * 16 + lrow;
      b[nj] = *(const short8*)&wef[((size_t)kb * 512 + n) * 8];
    }
#pragma unroll
    for (int mi = 0; mi < 4; ++mi)
#pragma unroll
      for (int nj = 0; nj < 4; ++nj)
        acc[mi][nj] = __builtin_amdgcn_mfma_f32_16x16x32_bf16(a[mi], b[nj], acc[mi][nj], 0, 0, 0);
  }

#pragma unroll
  for (int mi = 0; mi < 4; ++mi)
#pragma unroll
    for (int nj = 0; nj < 4; ++nj)
#pragma unroll
      for (int r = 0; r < 4; ++r) {
        int row = m0 + wr * 64 + mi * 16 + lkg * 4 + r;
        int col = n0 + wc * 64 + nj * 16 + lrow;
        atomicAdd(&C[(size_t)row * 512 + col], acc[mi][nj][r]);
      }
}

// ---------- dec3 weight conversion ----------
__global__ void conv_wf_k(const float* __restrict__ W, ushort* __restrict__ wf) {
  int n = blockIdx.x * 256 + threadIdx.x;
  int kb = blockIdx.y;
  if (n >= NPD) return;
  ushort v[8];
#pragma unroll
  for (int j = 0; j < 8; ++j)
    v[j] = (n < Nn) ? f2bf(W[(size_t)(8 * kb + j) * Nn + n]) : (ushort)0;
  uint4 pk;
  pk.x = (uint)v[0] | ((uint)v[1] << 16);
  pk.y = (uint)v[2] | ((uint)v[3] << 16);
  pk.z = (uint)v[4] | ((uint)v[5] << 16);
  pk.w = (uint)v[6] | ((uint)v[7] << 16);
  *(uint4*)&wf[((size_t)kb * NPD + n) * 8] = pk;
}

// ---------- dec3 fragment-major GEMM with 1-step prefetch ----------
__global__ __launch_bounds__(256) void fmg_dec3_k(const ushort* __restrict__ d2f,
                                                  const ushort* __restrict__ wf,
                                                  const float* __restrict__ bias,
                                                  float* __restrict__ C) {
  int n0 = blockIdx.x * 128, m0 = blockIdx.y * 128;
  int l = threadIdx.x & 63, w = threadIdx.x >> 6;
  int wr = w >> 1, wc = w & 1;
  int lrow = l & 15, lkg = l >> 4;
  f32x4 acc[4][4] = {};

  int m_0 = m0 + wr * 64 + lrow, n_0 = n0 + wc * 64 + lrow;
  // current + prefetch fragment registers (named, static)
  short8 a0, a1, a2, a3, b0, b1, b2, b3;
  short8 pa0, pa1, pa2, pa3, pb0, pb1, pb2, pb3;

#define LOADF(dst_a0, dst_a1, dst_a2, dst_a3, dst_b0, dst_b1, dst_b2, dst_b3, KB_)          \
  {                                                                                         \
    int kb_ = (KB_);                                                                        \
    dst_a0 = *(const short8*)&d2f[((size_t)kb_ * 512 + m_0) * 8];                           \
    dst_a1 = *(const short8*)&d2f[((size_t)kb_ * 512 + m_0 + 16) * 8];                      \
    dst_a2 = *(const short8*)&d2f[((size_t)kb_ * 512 + m_0 + 32) * 8];                      \
    dst_a3 = *(const short8*)&d2f[((size_t)kb_ * 512 + m_0 + 48) * 8];                      \
    dst_b0 = *(const short8*)&wf[((size_t)kb_ * NPD + n_0) * 8];                            \
    dst_b1 = *(const short8*)&wf[((size_t)kb_ * NPD + n_0 + 16) * 8];                       \
    dst_b2 = *(const short8*)&wf[((size_t)kb_ * NPD + n_0 + 32) * 8];                       \
    dst_b3 = *(const short8*)&wf[((size_t)kb_ * NPD + n_0 + 48) * 8];                       \
  }

  LOADF(a0, a1, a2, a3, b0, b1, b2, b3, lkg);

#pragma unroll 1
  for (int ks = 0; ks < 16; ++ks) {
    if (ks + 1 < 16)
      LOADF(pa0, pa1, pa2, pa3, pb0, pb1, pb2, pb3, (ks + 1) * 4 + lkg);
    acc[0][0] = __builtin_amdgcn_mfma_f32_16x16x32_bf16(a0, b0, acc[0][0], 0, 0, 0);
    acc[0][1] = __builtin_amdgcn_mfma_f32_16x16x32_bf16(a0, b1, acc[0][1], 0, 0, 0);
    acc[0][2] = __builtin_amdgcn_mfma_f32_16x16x32_bf16(a0, b2, acc[0][2], 0, 0, 0);
    acc[0][3] = __builtin_amdgcn_mfma_f32_16x16x32_bf16(a0, b3, acc[0][3], 0, 0, 0);
    acc[1][0] = __builtin_amdgcn_mfma_f32_16x16x32_bf16(a1, b0, acc[1][0], 0, 0, 0);
    acc[1][1] = __builtin_amdgcn_mfma_f32_16x16x32_bf16(a1, b1, acc[1][1], 0, 0, 0);
    acc[1][2] = __builtin_amdgcn_mfma_f32_16x16x32_bf16(a1, b2, acc[1][2], 0, 0, 0);
    acc[1][3] = __builtin_amdgcn_mfma_f32_16x16x32_bf16(a1, b3, acc[1][3], 0, 0, 0);
    acc[2][0] = __builtin_amdgcn_mfma_f32_16x16x32_bf16(a2, b0, acc[2][0], 0, 0, 0);
    acc[2][1] = __builtin_amdgcn_mfma_f32_16x16x32_bf16(a2, b1, acc[2][1], 0, 0, 0);
    acc[2][2] = __builtin_amdgcn_mfma_f32_16x16x32_bf16(a2, b2, acc[2][2], 0, 0, 0);
    acc[2][3] = __builtin_amdgcn_mfma_f32_16x16x32_bf16(a2, b3, acc[2][3], 0, 0, 0);
    acc[3][0] = __builtin_amdgcn_mfma_f32_16x16x32_bf16(a3, b0, acc[3][0], 0, 0, 0);
    acc[3][1] = __builtin_amdgcn_mfma_f32_16x16x32_bf16(a3, b1, acc[3][1], 0, 0, 0);
    acc[3][2] = __builtin_amdgcn_mfma_f32_16x16x32_bf16(a3, b2, acc[3][2], 0, 0, 0);
    acc[3][3] = __builtin_amdgcn_mfma_f32_16x16x32_bf16(a3, b3, acc[3][3], 0, 0, 0);
    a0 = pa0; a1 = pa1; a2 = pa2; a3 = pa3;
    b0 = pb0; b1 = pb1; b2 = pb2; b3 = pb3;
  }
#undef LOADF

#pragma unroll
  for (int mi = 0; mi < 4; ++mi)
#pragma unroll
    for (int nj = 0; nj < 4; ++nj)
#pragma unroll
      for (int r = 0; r < 4; ++r) {
        int row = m0 + wr * 64 + mi * 16 + lkg * 4 + r;
        int col = n0 + wc * 64 + nj * 16 + lrow;
        if (col < Nn) {
          float v = acc[mi][nj][r] + bias[col];
          C[(size_t)row * Nn + col] = LRELU(v);
        }
      }
}

// ---------- tail A: h1 -> h2 -> z (verified r16) ----------
__global__ __launch_bounds__(256) void tailA_k(const float* __restrict__ h1,
                                               const float* __restrict__ c1,
                                               const float* __restrict__ W2,
                                               const float* __restrict__ c2,
                                               const float* __restrict__ W3,
                                               const float* __restrict__ c3,
                                               float* __restrict__ zbuf,
                                               float* __restrict__ out_z) {
  __shared__ float s_h1[512];
  __shared__ float s_h2[256];
  __shared__ float s_part[4][256];
  int rl = blockIdx.x;
  int t = threadIdx.x;
  int w = t >> 6, l = t & 63;

  {
    float r0 = h1[(size_t)rl * 512 + t] + c1[t];
    float r1 = h1[(size_t)rl * 512 + t + 256] + c1[t + 256];
    s_h1[t] = LRELU(r0);
    s_h1[t + 256] = LRELU(r1);
  }
  __syncthreads();

  {
    int c4 = l * 4;
    float a0 = 0.f, a1 = 0.f, a2 = 0.f, a3 = 0.f;
#pragma unroll 16
    for (int k = w * 128; k < w * 128 + 128; ++k) {
      float4 wv = *(const float4*)&W2[(size_t)k * 256 + c4];
      float x = s_h1[k];
      a0 += x * wv.x; a1 += x * wv.y; a2 += x * wv.z; a3 += x * wv.w;
    }
    float4 pv = {a0, a1, a2, a3};
    *(float4*)&s_part[w][c4] = pv;
  }
  __syncthreads();
  s_h2[t] = LRELU(s_part[0][t] + s_part[1][t] + s_part[2][t] + s_part[3][t] + c2[t]);
  __syncthreads();

  {
    int c = t >> 2, p = t & 3;
    float a = 0.f;
#pragma unroll 16
    for (int k = p * 64; k < p * 64 + 64; ++k) a += s_h2[k] * W3[(size_t)k * 64 + c];
    s_part[p][c] = a;
  }
  __syncthreads();
  if (t < 64) {
    float v = s_part[0][t] + s_part[1][t] + s_part[2][t] + s_part[3][t] + c3[t];
    v = LRELU(v);
    zbuf[(size_t)rl * 64 + t] = v;
    out_z[(size_t)rl * 64 + t] = v;
  }
}

// ---------- tail B: dec path | disc path (verified r16) ----------
__global__ __launch_bounds__(256) void tailB_k(
    const float* __restrict__ zbuf, const float* __restrict__ Wd1, const float* __restrict__ cd1,
    const float* __restrict__ Wd2, const float* __restrict__ cd2, const float* __restrict__ Wg1,
    const float* __restrict__ cg1, const float* __restrict__ Wg2, const float* __restrict__ cg2,
    const float* __restrict__ Wg3, const float* __restrict__ cg3, float* __restrict__ out_d,
    ushort* __restrict__ d2f) {
  __shared__ float s_z[64];
  __shared__ float s_x[256];
  __shared__ float s_part[4][256];
  __shared__ float s_g2[256];
  __shared__ float s_red[4];
  int bid = blockIdx.x;
  int rl = bid & 511;
  int t = threadIdx.x;
  int w = t >> 6, l = t & 63;

  if (t < 64) s_z[t] = zbuf[(size_t)rl * 64 + t];
  __syncthreads();

  if (bid < 512) {
    {
      float a = 0.f;
#pragma unroll
      for (int k = 0; k < 64; ++k) a += s_z[k] * Wd1[(size_t)k * 256 + t];
      s_x[t] = LRELU(a + cd1[t]);
    }
    __syncthreads();
    {
      int g = t & 127, p = t >> 7;
      int c4 = g * 4;
      float a0 = 0.f, a1 = 0.f, a2 = 0.f, a3 = 0.f;
#pragma unroll 16
      for (int k = p * 128; k < p * 128 + 128; ++k) {
        float4 wv = *(const float4*)&Wd2[(size_t)k * 512 + c4];
        float x = s_x[k];
        a0 += x * wv.x; a1 += x * wv.y; a2 += x * wv.z; a3 += x * wv.w;
      }
      float* sp = &s_part[0][0];
      float4 pv = {a0, a1, a2, a3};
      *(float4*)&sp[p * 512 + c4] = pv;
    }
    __syncthreads();
    {
      const float* sp = &s_part[0][0];
#pragma unroll
      for (int cc = 0; cc < 2; ++cc) {
        int c = t + cc * 256;
        float v = sp[c] + sp[512 + c] + cd2[c];
        v = LRELU(v);
        d2f[((size_t)(c >> 3) * 512 + rl) * 8 + (c & 7)] = f2bf(v);
      }
    }
  } else {
    {
      float a = 0.f;
#pragma unroll
      for (int k = 0; k < 64; ++k) a += s_z[k] * Wg1[(size_t)k * 256 + t];
      s_x[t] = LRELU(a + cg1[t]);
    }
    __syncthreads();
    {
      int c4 = l * 4;
      float a0 = 0.f, a1 = 0.f, a2 = 0.f, a3 = 0.f;
#pragma unroll 16
      for (int k = w * 64; k < w * 64 + 64; ++k) {
        float4 wv = *(const float4*)&Wg2[(size_t)k * 256 + c4];
        float x = s_x[k];
        a0 += x * wv.x; a1 += x * wv.y; a2 += x * wv.z; a3 += x * wv.w;
      }
      float4 pv = {a0, a1, a2, a3};
      *(float4*)&s_part[w][c4] = pv;
    }
    __syncthreads();
    s_g2[t] = LRELU(s_part[0][t] + s_part[1][t] + s_part[2][t] + s_part[3][t] + cg2[t]);
    __syncthreads();
    {
      float p = s_g2[t] * Wg3[t];
#pragma unroll
      for (int o = 32; o > 0; o >>= 1) p += __shfl_down(p, o);
      if ((t & 63) == 0) s_red[t >> 6] = p;
      __syncthreads();
      if (t == 0) {
        float s = s_red[0] + s_red[1] + s_red[2] + s_red[3] + cg3[0];
        out_d[rl] = 1.f / (1.f + __expf(-s));
      }
    }
  }
}

// ---------- sentinels ----------
__global__ void sentinel_k(float* out, float val) { out[0] = val; }
__global__ void flag_sentinel_k(float* out, const int* flag) {
  if (*flag != 0) out[0] = 70000.0f;
}

extern "C" void kernel_launch(void* const* d_in, const int* in_sizes, int n_in,
                              void* d_out, int out_size, void* d_ws, size_t ws_size,
                              hipStream_t stream) {
  const float* data = (const float*)d_in[0];
  const float* noise = (const float*)d_in[1];
  const int* edge = (const int*)d_in[2];
  const int* esrc_in = edge;
  const int* edst_in = edge + Ee;
  const float* w_gcn = (const float*)d_in[3];
  const float* b_gcn = (const float*)d_in[4];
  const float* enc1_w = (const float*)d_in[5];
  const float* enc1_b = (const float*)d_in[6];
  const float* enc2_w = (const float*)d_in[7];
  const float* enc2_b = (const float*)d_in[8];
  const float* enc3_w = (const float*)d_in[9];
  const float* enc3_b = (const float*)d_in[10];
  const float* dec1_w = (const float*)d_in[11];
  const float* dec1_b = (const float*)d_in[12];
  const float* dec2_w = (const float*)d_in[13];
  const float* dec2_b = (const float*)d_in[14];
  const float* dec3_w = (const float*)d_in[15];
  const float* dec3_b = (const float*)d_in[16];
  const float* disc1_w = (const float*)d_in[17];
  const float* disc1_b = (const float*)d_in[18];
  const float* disc2_w = (const float*)d_in[19];
  const float* disc2_b = (const float*)d_in[20];
  const float* disc3_w = (const float*)d_in[21];
  const float* disc3_b = (const float*)d_in[22];

  char* w = (char*)d_ws;
  size_t o = 0;
  auto alloc = [&](size_t bytes) {
    size_t r = o;
    o = (o + bytes + 15) & ~(size_t)15;
    return r;
  };
  size_t r1 = alloc((size_t)64 * NPD * 8 * 2);
  ushort* xs = (ushort*)(w + r1);
  ushort* wef = (ushort*)(w + r1);
  ushort* wf = (ushort*)(w + r1);
  ushort* gfm = (ushort*)(w + alloc((size_t)KBn * 512 * 8 * 2));
  float* h1 = (float*)(w + alloc(512 * 512 * 4));
  ushort* d2f = (ushort*)(w + alloc((size_t)64 * 512 * 8 * 2));
  float* zbuf = (float*)(w + alloc((size_t)512 * 64 * 4));
  float* dinv = (float*)(w + alloc(Nn * 4));
  int* cnt = (int*)(w + alloc(Nn * 4));
  int* offs = (int*)(w + alloc(Nn * 4));
  int* cursor = (int*)(w + alloc(Nn * 4));
  uint* eOff = (uint*)(w + alloc(Ee * 4));
  int* flag = (int*)(w + alloc(16));

  float* outp = (float*)d_out;
  float* out_dec = outp;
  float* out_z = outp + (size_t)Bb * Nn;
  float* out_d = out_z + (size_t)Bb * 64;

  static const int expect_sizes[23] = {
      10240000, 10240000, 1280000, 1, 1,
      10240000, 512, 131072, 256, 16384, 64,
      16384, 256, 131072, 512, 10240000, 20000,
      16384, 256, 65536, 256, 256, 1};
  float host_sentinel = 0.f;
  if (n_in != 23) host_sentinel = 50000.f;
  else if (out_size != 10273280) host_sentinel = 80000.f;
  else if (ws_size < 46100000u) host_sentinel = 60000.f;
  else {
    for (int i = 0; i < 23; ++i)
      if (in_sizes[i] != expect_sizes[i]) { host_sentinel = 100000.f + 1000.f * i; break; }
  }

  // ---- CSR build ----
  hipMemsetAsync(cnt, 0, Nn * sizeof(int), stream);
  hipMemsetAsync(flag, 0, 2 * sizeof(int), stream);
  hipMemsetAsync(h1, 0, 512 * 512 * 4, stream);
  hist_check_k<<<(Ee + 255) / 256, 256, 0, stream>>>(esrc_in, edst_in, Ee, cnt, flag);
  offs_k<<<(Nn + 255) / 256, 256, 0, stream>>>(cnt, offs, cursor, dinv, flag + 1);
  scatter_k<<<(Ee + 255) / 256, 256, 0, stream>>>(esrc_in, edst_in, Ee, cursor, eOff);

  // ---- pipeline ----
  {
    dim3 g((Nn + 63) / 64, 8);
    transpose_xs_k<<<g, 256, 0, stream>>>(data, noise, dinv, xs);
  }
  spmm_fm_k<<<(Nn / 8) * 4, 256, 0, stream>>>(xs, eOff, offs, cnt, dinv, w_gcn, b_gcn, gfm);
  {
    dim3 g(2, KBn);
    conv_we_k<<<g, 256, 0, stream>>>(enc1_w, wef);
  }
  {
    // enc1: splitK 63 x 10 K-steps (625 total)
    dim3 g(512 / 128, 512 / 128, 63);
    fmg_enc1_k<<<g, 256, 0, stream>>>(gfm, wef, h1);
  }
  tailA_k<<<Bb, 256, 0, stream>>>(h1, enc1_b, enc2_w, enc2_b, enc3_w, enc3_b, zbuf, out_z);
  tailB_k<<<2 * Bb, 256, 0, stream>>>(zbuf, dec1_w, dec1_b, dec2_w, dec2_b, disc1_w, disc1_b,
                                      disc2_w, disc2_b, disc3_w, disc3_b, out_d, d2f);
  {
    dim3 g((NPD + 255) / 256, 64);
    conv_wf_k<<<g, 256, 0, stream>>>(dec3_w, wf);
  }
  {
    dim3 g(NPD / 128, 512 / 128);
    fmg_dec3_k<<<g, 256, 0, stream>>>(d2f, wf, dec3_b, out_dec);
  }

  flag_sentinel_k<<<1, 1, 0, stream>>>(out_dec, flag);
  if (host_sentinel != 0.f) sentinel_k<<<1, 1, 0, stream>>>(out_dec, host_sentinel);
}

// Round 18
// 279.540 us; speedup vs baseline: 1.1180x; 1.1180x over previous
//
#include <hip/hip_runtime.h>
#include <hip/hip_bf16.h>

// AAE_GCN round 18: revert r17 experiments (splitK63 atomics +15us, dec3-prefetch/
//  spmm-uint2 suspected for +13us) back to r16 base, plus ONE change:
//  enc1 atomic splitK -> 16 partial tiles (plain stores) + reduce16_k.
//  Adaptive: falls back to r16 atomic path if ws_size < ~61.7MB.

#define LRELU(v) ((v) > 0.f ? (v) : 0.01f * (v))

static constexpr int Bb = 512;
static constexpr int Nn = 20000;
static constexpr int Ee = 640000;
static constexpr int KBn = 2500;
static constexpr int NPD = 20096;

typedef __attribute__((ext_vector_type(8))) short short8;
typedef __attribute__((ext_vector_type(4))) float f32x4;

__device__ __forceinline__ ushort f2bf(float f) {
  uint u = __builtin_bit_cast(uint, f);
  u = u + 0x7FFFu + ((u >> 16) & 1u);  // RTNE
  return (ushort)(u >> 16);
}
__device__ __forceinline__ float bfLo(uint u) {
  return __builtin_bit_cast(float, u << 16);
}
__device__ __forceinline__ float bfHi(uint u) {
  return __builtin_bit_cast(float, u & 0xffff0000u);
}

// ---------- transpose + noise + dinv-fold -> xs chunks [4][Nn][128] bf16 ----------
__global__ void transpose_xs_k(const float* __restrict__ a, const float* __restrict__ nz,
                               const float* __restrict__ dinv, ushort* __restrict__ xs) {
  __shared__ ushort tile[64][65];
  int c0 = blockIdx.x * 64;
  int p = blockIdx.y;
  int chunk = p >> 1;
  int sub = (p & 1) * 64;
  int rbase = p * 64;
  for (int i = threadIdx.x; i < 64 * 64; i += 256) {
    int rr = i >> 6, cc = i & 63;
    int r = rbase + rr, c = c0 + cc;
    ushort v = 0;
    if (c < Nn) {
      size_t idx = (size_t)r * Nn + c;
      v = f2bf(dinv[c] * (a[idx] + 0.1f * nz[idx]));
    }
    tile[rr][cc] = v;
  }
  __syncthreads();
  for (int i = threadIdx.x; i < 64 * 64; i += 256) {
    int cc = i >> 6, rr = i & 63;
    int c = c0 + cc;
    if (c < Nn) xs[(size_t)chunk * Nn * 128 + (size_t)c * 128 + sub + rr] = tile[rr][cc];
  }
}

// ---------- degree histogram + range check ----------
__global__ void hist_check_k(const int* __restrict__ src, const int* __restrict__ dst, int E,
                             int* __restrict__ cnt, int* __restrict__ flag) {
  int i = blockIdx.x * 256 + threadIdx.x;
  if (i < E) {
    int s = src[i], d = dst[i];
    if ((unsigned)s >= (unsigned)Nn || (unsigned)d >= (unsigned)Nn) {
      atomicExch(flag, 1);
    } else {
      atomicAdd(&cnt[d], 1);
    }
  }
}

// ---------- offsets via wave prefix + atomic bump ----------
__global__ void offs_k(const int* __restrict__ cnt, int* __restrict__ offs,
                       int* __restrict__ cursor, float* __restrict__ dinv,
                       int* __restrict__ bump) {
  int i = blockIdx.x * 256 + threadIdx.x;
  int l = threadIdx.x & 63;
  int v = (i < Nn) ? cnt[i] : 0;
  int x = v;
#pragma unroll
  for (int d = 1; d < 64; d <<= 1) {
    int t = __shfl_up(x, d);
    if (l >= d) x += t;
  }
  int total = __shfl(x, 63);
  int base = 0;
  if (l == 0) base = atomicAdd(bump, total);
  base = __shfl(base, 0);
  int excl = base + x - v;
  if (i < Nn) {
    offs[i] = excl;
    cursor[i] = excl;
    dinv[i] = rsqrtf(2.0f + (float)v);
  }
}

// ---------- scatter edges (byte offsets of 256B chunk rows) ----------
__global__ void scatter_k(const int* __restrict__ src, const int* __restrict__ dst, int E,
                          int* __restrict__ cursor, uint* __restrict__ eOff) {
  int i = blockIdx.x * 256 + threadIdx.x;
  if (i < E) {
    int s = src[i], d = dst[i];
    if ((unsigned)s >= (unsigned)Nn || (unsigned)d >= (unsigned)Nn) return;
    int p = atomicAdd(&cursor[d], 1);
    eOff[p] = (uint)s * 256u;
  }
}

// ---------- SpMM fm output, 16-deep gather batches (verified r15/r16) ----------
__global__ __launch_bounds__(256) void spmm_fm_k(
    const ushort* __restrict__ xs, const uint* __restrict__ eOff, const int* __restrict__ offs,
    const int* __restrict__ cnt, const float* __restrict__ dinv, const float* __restrict__ wg,
    const float* __restrict__ bg, ushort* __restrict__ gfm) {
  __shared__ uint sIdx[4][64];
  __shared__ ushort sOut[128][8];
  int bid = blockIdx.x;
  int chunk = bid & 3;
  int grp = bid >> 2;
  int wv = threadIdx.x >> 6, l = threadIdx.x & 63;
  const char* base = (const char*)(xs + (size_t)chunk * Nn * 128) + l * 4;
  float wgv = wg[0], bb = bg[0];

#pragma unroll
  for (int sub = 0; sub < 2; ++sub) {
    int n = grp * 8 + wv * 2 + sub;
    int o = offs[n], c = cnt[n];
    const uint* ep = eOff + o;
    uint su = *(const uint*)(base + (size_t)n * 256);
    float a00 = 2.0f * bfLo(su), a01 = 2.0f * bfHi(su);
    float a10 = 0.f, a11 = 0.f;

    for (int bi = 0; bi < c; bi += 64) {
      int rem = c - bi;
      if (rem > 64) rem = 64;
      sIdx[wv][l] = (l < rem) ? ep[bi + l] : 0u;
      int i = 0;
      for (; i + 16 <= rem; i += 16) {
        uint u[16];
#pragma unroll
        for (int j = 0; j < 16; ++j) u[j] = *(const uint*)(base + sIdx[wv][i + j]);
#pragma unroll
        for (int j = 0; j < 16; j += 2) {
          a00 += bfLo(u[j]);
          a01 += bfHi(u[j]);
          a10 += bfLo(u[j + 1]);
          a11 += bfHi(u[j + 1]);
        }
      }
      for (; i + 4 <= rem; i += 4) {
        uint u0 = *(const uint*)(base + sIdx[wv][i]);
        uint u1 = *(const uint*)(base + sIdx[wv][i + 1]);
        uint u2 = *(const uint*)(base + sIdx[wv][i + 2]);
        uint u3 = *(const uint*)(base + sIdx[wv][i + 3]);
        a00 += bfLo(u0);
        a01 += bfHi(u0);
        a10 += bfLo(u1);
        a11 += bfHi(u1);
        a00 += bfLo(u2);
        a01 += bfHi(u2);
        a10 += bfLo(u3);
        a11 += bfHi(u3);
      }
      for (; i < rem; ++i) {
        uint u = *(const uint*)(base + sIdx[wv][i]);
        a00 += bfLo(u);
        a01 += bfHi(u);
      }
    }

    float wdn = wgv * dinv[n];
    float v0 = wdn * (a00 + a10) + bb;
    float v1 = wdn * (a01 + a11) + bb;
    v0 = LRELU(v0);
    v1 = LRELU(v1);
    int j = wv * 2 + sub;
    sOut[2 * l][j] = f2bf(v0);
    sOut[2 * l + 1][j] = f2bf(v1);
  }
  __syncthreads();
  int row = threadIdx.x >> 1, half = threadIdx.x & 1;
  uint2 v = *(const uint2*)&sOut[row][half * 4];
  int m = chunk * 128 + row;
  *(uint2*)&gfm[((size_t)grp * 512 + m) * 8 + half * 4] = v;
}

// ---------- enc1_w -> bf16 fragment-major ----------
__global__ void conv_we_k(const float* __restrict__ W, ushort* __restrict__ wef) {
  int n = blockIdx.x * 256 + threadIdx.x;
  int kb = blockIdx.y;
  ushort v[8];
#pragma unroll
  for (int j = 0; j < 8; ++j) v[j] = f2bf(W[(size_t)(8 * kb + j) * 512 + n]);
  uint4 pk;
  pk.x = (uint)v[0] | ((uint)v[1] << 16);
  pk.y = (uint)v[2] | ((uint)v[3] << 16);
  pk.z = (uint)v[4] | ((uint)v[5] << 16);
  pk.w = (uint)v[6] | ((uint)v[7] << 16);
  *(uint4*)&wef[((size_t)kb * 512 + n) * 8] = pk;
}

// ---------- enc1 fragment-major GEMM ----------
// PART=true: write full 512x512 f32 tile into Cp + z*512*512 (plain stores),
//            K-slice [(z*625)>>4, ((z+1)*625)>>4).
// PART=false: r16 atomic path, splitK 25 x 25 ks.
template <bool PART>
__global__ __launch_bounds__(256) void fmg_enc1_k(const ushort* __restrict__ gfm,
                                                  const ushort* __restrict__ wef,
                                                  float* __restrict__ C) {
  int n0 = blockIdx.x * 128, m0 = blockIdx.y * 128;
  int z = blockIdx.z;
  int l = threadIdx.x & 63, w = threadIdx.x >> 6;
  int wr = w >> 1, wc = w & 1;
  int lrow = l & 15, lkg = l >> 4;
  f32x4 acc[4][4] = {};
  int ksBeg, ksEnd;
  if (PART) {
    ksBeg = (z * 625) >> 4;
    ksEnd = ((z + 1) * 625) >> 4;
  } else {
    ksBeg = z * 25;
    ksEnd = ksBeg + 25;
  }

  for (int ks = ksBeg; ks < ksEnd; ++ks) {
    int kb = ks * 4 + lkg;
    short8 a[4], b[4];
#pragma unroll
    for (int mi = 0; mi < 4; ++mi) {
      int m = m0 + wr * 64 + mi * 16 + lrow;
      a[mi] = *(const short8*)&gfm[((size_t)kb * 512 + m) * 8];
    }
#pragma unroll
    for (int nj = 0; nj < 4; ++nj) {
      int n = n0 + wc * 64 + nj * 16 + lrow;
      b[nj] = *(const short8*)&wef[((size_t)kb * 512 + n) * 8];
    }
#pragma unroll
    for (int mi = 0; mi < 4; ++mi)
#pragma unroll
      for (int nj = 0; nj < 4; ++nj)
        acc[mi][nj] = __builtin_amdgcn_mfma_f32_16x16x32_bf16(a[mi], b[nj], acc[mi][nj], 0, 0, 0);
  }

  float* Cb = PART ? (C + (size_t)z * 512 * 512) : C;
#pragma unroll
  for (int mi = 0; mi < 4; ++mi)
#pragma unroll
    for (int nj = 0; nj < 4; ++nj)
#pragma unroll
      for (int r = 0; r < 4; ++r) {
        int row = m0 + wr * 64 + mi * 16 + lkg * 4 + r;
        int col = n0 + wc * 64 + nj * 16 + lrow;
        if (PART)
          Cb[(size_t)row * 512 + col] = acc[mi][nj][r];
        else
          atomicAdd(&Cb[(size_t)row * 512 + col], acc[mi][nj][r]);
      }
}

// ---------- reduce 16 partial tiles -> h1 ----------
__global__ void reduce16_k(const float* __restrict__ Cp, float* __restrict__ h1) {
  int i = blockIdx.x * 256 + threadIdx.x;  // 0 .. 512*512-1
  float s = 0.f;
#pragma unroll
  for (int z = 0; z < 16; ++z) s += Cp[(size_t)z * 512 * 512 + i];
  h1[i] = s;
}

// ---------- dec3 weight conversion (verified r12-r16) ----------
__global__ void conv_wf_k(const float* __restrict__ W, ushort* __restrict__ wf) {
  int n = blockIdx.x * 256 + threadIdx.x;
  int kb = blockIdx.y;
  if (n >= NPD) return;
  ushort v[8];
#pragma unroll
  for (int j = 0; j < 8; ++j)
    v[j] = (n < Nn) ? f2bf(W[(size_t)(8 * kb + j) * Nn + n]) : (ushort)0;
  uint4 pk;
  pk.x = (uint)v[0] | ((uint)v[1] << 16);
  pk.y = (uint)v[2] | ((uint)v[3] << 16);
  pk.z = (uint)v[4] | ((uint)v[5] << 16);
  pk.w = (uint)v[6] | ((uint)v[7] << 16);
  *(uint4*)&wf[((size_t)kb * NPD + n) * 8] = pk;
}

// ---------- dec3 fragment-major GEMM (r16 verbatim — prefetch reverted) ----------
__global__ __launch_bounds__(256) void fmg_dec3_k(const ushort* __restrict__ d2f,
                                                  const ushort* __restrict__ wf,
                                                  const float* __restrict__ bias,
                                                  float* __restrict__ C) {
  int n0 = blockIdx.x * 128, m0 = blockIdx.y * 128;
  int l = threadIdx.x & 63, w = threadIdx.x >> 6;
  int wr = w >> 1, wc = w & 1;
  int lrow = l & 15, lkg = l >> 4;
  f32x4 acc[4][4] = {};

#pragma unroll 4
  for (int ks = 0; ks < 16; ++ks) {
    int kb = ks * 4 + lkg;
    short8 a[4], b[4];
#pragma unroll
    for (int mi = 0; mi < 4; ++mi) {
      int m = m0 + wr * 64 + mi * 16 + lrow;
      a[mi] = *(const short8*)&d2f[((size_t)kb * 512 + m) * 8];
    }
#pragma unroll
    for (int nj = 0; nj < 4; ++nj) {
      int n = n0 + wc * 64 + nj * 16 + lrow;
      b[nj] = *(const short8*)&wf[((size_t)kb * NPD + n) * 8];
    }
#pragma unroll
    for (int mi = 0; mi < 4; ++mi)
#pragma unroll
      for (int nj = 0; nj < 4; ++nj)
        acc[mi][nj] = __builtin_amdgcn_mfma_f32_16x16x32_bf16(a[mi], b[nj], acc[mi][nj], 0, 0, 0);
  }

#pragma unroll
  for (int mi = 0; mi < 4; ++mi)
#pragma unroll
    for (int nj = 0; nj < 4; ++nj)
#pragma unroll
      for (int r = 0; r < 4; ++r) {
        int row = m0 + wr * 64 + mi * 16 + lkg * 4 + r;
        int col = n0 + wc * 64 + nj * 16 + lrow;
        if (col < Nn) {
          float v = acc[mi][nj][r] + bias[col];
          C[(size_t)row * Nn + col] = LRELU(v);
        }
      }
}

// ---------- tail A: h1 -> h2 -> z (verified r16) ----------
__global__ __launch_bounds__(256) void tailA_k(const float* __restrict__ h1,
                                               const float* __restrict__ c1,
                                               const float* __restrict__ W2,
                                               const float* __restrict__ c2,
                                               const float* __restrict__ W3,
                                               const float* __restrict__ c3,
                                               float* __restrict__ zbuf,
                                               float* __restrict__ out_z) {
  __shared__ float s_h1[512];
  __shared__ float s_h2[256];
  __shared__ float s_part[4][256];
  int rl = blockIdx.x;
  int t = threadIdx.x;
  int w = t >> 6, l = t & 63;

  {
    float r0 = h1[(size_t)rl * 512 + t] + c1[t];
    float r1 = h1[(size_t)rl * 512 + t + 256] + c1[t + 256];
    s_h1[t] = LRELU(r0);
    s_h1[t + 256] = LRELU(r1);
  }
  __syncthreads();

  {
    int c4 = l * 4;
    float a0 = 0.f, a1 = 0.f, a2 = 0.f, a3 = 0.f;
#pragma unroll 16
    for (int k = w * 128; k < w * 128 + 128; ++k) {
      float4 wv = *(const float4*)&W2[(size_t)k * 256 + c4];
      float x = s_h1[k];
      a0 += x * wv.x; a1 += x * wv.y; a2 += x * wv.z; a3 += x * wv.w;
    }
    float4 pv = {a0, a1, a2, a3};
    *(float4*)&s_part[w][c4] = pv;
  }
  __syncthreads();
  s_h2[t] = LRELU(s_part[0][t] + s_part[1][t] + s_part[2][t] + s_part[3][t] + c2[t]);
  __syncthreads();

  {
    int c = t >> 2, p = t & 3;
    float a = 0.f;
#pragma unroll 16
    for (int k = p * 64; k < p * 64 + 64; ++k) a += s_h2[k] * W3[(size_t)k * 64 + c];
    s_part[p][c] = a;
  }
  __syncthreads();
  if (t < 64) {
    float v = s_part[0][t] + s_part[1][t] + s_part[2][t] + s_part[3][t] + c3[t];
    v = LRELU(v);
    zbuf[(size_t)rl * 64 + t] = v;
    out_z[(size_t)rl * 64 + t] = v;
  }
}

// ---------- tail B: dec path | disc path (verified r16) ----------
__global__ __launch_bounds__(256) void tailB_k(
    const float* __restrict__ zbuf, const float* __restrict__ Wd1, const float* __restrict__ cd1,
    const float* __restrict__ Wd2, const float* __restrict__ cd2, const float* __restrict__ Wg1,
    const float* __restrict__ cg1, const float* __restrict__ Wg2, const float* __restrict__ cg2,
    const float* __restrict__ Wg3, const float* __restrict__ cg3, float* __restrict__ out_d,
    ushort* __restrict__ d2f) {
  __shared__ float s_z[64];
  __shared__ float s_x[256];
  __shared__ float s_part[4][256];
  __shared__ float s_g2[256];
  __shared__ float s_red[4];
  int bid = blockIdx.x;
  int rl = bid & 511;
  int t = threadIdx.x;
  int w = t >> 6, l = t & 63;

  if (t < 64) s_z[t] = zbuf[(size_t)rl * 64 + t];
  __syncthreads();

  if (bid < 512) {
    {
      float a = 0.f;
#pragma unroll
      for (int k = 0; k < 64; ++k) a += s_z[k] * Wd1[(size_t)k * 256 + t];
      s_x[t] = LRELU(a + cd1[t]);
    }
    __syncthreads();
    {
      int g = t & 127, p = t >> 7;
      int c4 = g * 4;
      float a0 = 0.f, a1 = 0.f, a2 = 0.f, a3 = 0.f;
#pragma unroll 16
      for (int k = p * 128; k < p * 128 + 128; ++k) {
        float4 wv = *(const float4*)&Wd2[(size_t)k * 512 + c4];
        float x = s_x[k];
        a0 += x * wv.x; a1 += x * wv.y; a2 += x * wv.z; a3 += x * wv.w;
      }
      float* sp = &s_part[0][0];
      float4 pv = {a0, a1, a2, a3};
      *(float4*)&sp[p * 512 + c4] = pv;
    }
    __syncthreads();
    {
      const float* sp = &s_part[0][0];
#pragma unroll
      for (int cc = 0; cc < 2; ++cc) {
        int c = t + cc * 256;
        float v = sp[c] + sp[512 + c] + cd2[c];
        v = LRELU(v);
        d2f[((size_t)(c >> 3) * 512 + rl) * 8 + (c & 7)] = f2bf(v);
      }
    }
  } else {
    {
      float a = 0.f;
#pragma unroll
      for (int k = 0; k < 64; ++k) a += s_z[k] * Wg1[(size_t)k * 256 + t];
      s_x[t] = LRELU(a + cg1[t]);
    }
    __syncthreads();
    {
      int c4 = l * 4;
      float a0 = 0.f, a1 = 0.f, a2 = 0.f, a3 = 0.f;
#pragma unroll 16
      for (int k = w * 64; k < w * 64 + 64; ++k) {
        float4 wv = *(const float4*)&Wg2[(size_t)k * 256 + c4];
        float x = s_x[k];
        a0 += x * wv.x; a1 += x * wv.y; a2 += x * wv.z; a3 += x * wv.w;
      }
      float4 pv = {a0, a1, a2, a3};
      *(float4*)&s_part[w][c4] = pv;
    }
    __syncthreads();
    s_g2[t] = LRELU(s_part[0][t] + s_part[1][t] + s_part[2][t] + s_part[3][t] + cg2[t]);
    __syncthreads();
    {
      float p = s_g2[t] * Wg3[t];
#pragma unroll
      for (int o = 32; o > 0; o >>= 1) p += __shfl_down(p, o);
      if ((t & 63) == 0) s_red[t >> 6] = p;
      __syncthreads();
      if (t == 0) {
        float s = s_red[0] + s_red[1] + s_red[2] + s_red[3] + cg3[0];
        out_d[rl] = 1.f / (1.f + __expf(-s));
      }
    }
  }
}

// ---------- sentinels ----------
__global__ void sentinel_k(float* out, float val) { out[0] = val; }
__global__ void flag_sentinel_k(float* out, const int* flag) {
  if (*flag != 0) out[0] = 70000.0f;
}

extern "C" void kernel_launch(void* const* d_in, const int* in_sizes, int n_in,
                              void* d_out, int out_size, void* d_ws, size_t ws_size,
                              hipStream_t stream) {
  const float* data = (const float*)d_in[0];
  const float* noise = (const float*)d_in[1];
  const int* edge = (const int*)d_in[2];
  const int* esrc_in = edge;
  const int* edst_in = edge + Ee;
  const float* w_gcn = (const float*)d_in[3];
  const float* b_gcn = (const float*)d_in[4];
  const float* enc1_w = (const float*)d_in[5];
  const float* enc1_b = (const float*)d_in[6];
  const float* enc2_w = (const float*)d_in[7];
  const float* enc2_b = (const float*)d_in[8];
  const float* enc3_w = (const float*)d_in[9];
  const float* enc3_b = (const float*)d_in[10];
  const float* dec1_w = (const float*)d_in[11];
  const float* dec1_b = (const float*)d_in[12];
  const float* dec2_w = (const float*)d_in[13];
  const float* dec2_b = (const float*)d_in[14];
  const float* dec3_w = (const float*)d_in[15];
  const float* dec3_b = (const float*)d_in[16];
  const float* disc1_w = (const float*)d_in[17];
  const float* disc1_b = (const float*)d_in[18];
  const float* disc2_w = (const float*)d_in[19];
  const float* disc2_b = (const float*)d_in[20];
  const float* disc3_w = (const float*)d_in[21];
  const float* disc3_b = (const float*)d_in[22];

  char* w = (char*)d_ws;
  size_t o = 0;
  auto alloc = [&](size_t bytes) {
    size_t r = o;
    o = (o + bytes + 15) & ~(size_t)15;
    return r;
  };
  size_t r1 = alloc((size_t)64 * NPD * 8 * 2);
  ushort* xs = (ushort*)(w + r1);
  ushort* wef = (ushort*)(w + r1);
  ushort* wf = (ushort*)(w + r1);
  ushort* gfm = (ushort*)(w + alloc((size_t)KBn * 512 * 8 * 2));
  float* h1 = (float*)(w + alloc(512 * 512 * 4));
  ushort* d2f = (ushort*)(w + alloc((size_t)64 * 512 * 8 * 2));
  float* zbuf = (float*)(w + alloc((size_t)512 * 64 * 4));
  float* dinv = (float*)(w + alloc(Nn * 4));
  int* cnt = (int*)(w + alloc(Nn * 4));
  int* offs = (int*)(w + alloc(Nn * 4));
  int* cursor = (int*)(w + alloc(Nn * 4));
  uint* eOff = (uint*)(w + alloc(Ee * 4));
  int* flag = (int*)(w + alloc(16));
  size_t needBase = o;
  float* Cp = (float*)(w + alloc((size_t)16 * 512 * 512 * 4));  // 16MB partials
  size_t needPart = o;
  bool usePart = (ws_size >= needPart);

  float* outp = (float*)d_out;
  float* out_dec = outp;
  float* out_z = outp + (size_t)Bb * Nn;
  float* out_d = out_z + (size_t)Bb * 64;

  static const int expect_sizes[23] = {
      10240000, 10240000, 1280000, 1, 1,
      10240000, 512, 131072, 256, 16384, 64,
      16384, 256, 131072, 512, 10240000, 20000,
      16384, 256, 65536, 256, 256, 1};
  float host_sentinel = 0.f;
  if (n_in != 23) host_sentinel = 50000.f;
  else if (out_size != 10273280) host_sentinel = 80000.f;
  else if (ws_size < needBase) host_sentinel = 60000.f;
  else {
    for (int i = 0; i < 23; ++i)
      if (in_sizes[i] != expect_sizes[i]) { host_sentinel = 100000.f + 1000.f * i; break; }
  }

  // ---- CSR build ----
  hipMemsetAsync(cnt, 0, Nn * sizeof(int), stream);
  hipMemsetAsync(flag, 0, 2 * sizeof(int), stream);
  if (!usePart) hipMemsetAsync(h1, 0, 512 * 512 * 4, stream);
  hist_check_k<<<(Ee + 255) / 256, 256, 0, stream>>>(esrc_in, edst_in, Ee, cnt, flag);
  offs_k<<<(Nn + 255) / 256, 256, 0, stream>>>(cnt, offs, cursor, dinv, flag + 1);
  scatter_k<<<(Ee + 255) / 256, 256, 0, stream>>>(esrc_in, edst_in, Ee, cursor, eOff);

  // ---- pipeline ----
  {
    dim3 g((Nn + 63) / 64, 8);
    transpose_xs_k<<<g, 256, 0, stream>>>(data, noise, dinv, xs);
  }
  spmm_fm_k<<<(Nn / 8) * 4, 256, 0, stream>>>(xs, eOff, offs, cnt, dinv, w_gcn, b_gcn, gfm);
  {
    dim3 g(2, KBn);
    conv_we_k<<<g, 256, 0, stream>>>(enc1_w, wef);
  }
  if (usePart) {
    dim3 g(512 / 128, 512 / 128, 16);
    fmg_enc1_k<true><<<g, 256, 0, stream>>>(gfm, wef, Cp);
    reduce16_k<<<(512 * 512) / 256, 256, 0, stream>>>(Cp, h1);
  } else {
    dim3 g(512 / 128, 512 / 128, 25);
    fmg_enc1_k<false><<<g, 256, 0, stream>>>(gfm, wef, h1);
  }
  tailA_k<<<Bb, 256, 0, stream>>>(h1, enc1_b, enc2_w, enc2_b, enc3_w, enc3_b, zbuf, out_z);
  tailB_k<<<2 * Bb, 256, 0, stream>>>(zbuf, dec1_w, dec1_b, dec2_w, dec2_b, disc1_w, disc1_b,
                                      disc2_w, disc2_b, disc3_w, disc3_b, out_d, d2f);
  {
    dim3 g((NPD + 255) / 256, 64);
    conv_wf_k<<<g, 256, 0, stream>>>(dec3_w, wf);
  }
  {
    dim3 g(NPD / 128, 512 / 128);
    fmg_dec3_k<<<g, 256, 0, stream>>>(d2f, wf, dec3_b, out_dec);
  }

  flag_sentinel_k<<<1, 1, 0, stream>>>(out_dec, flag);
  if (host_sentinel != 0.f) sentinel_k<<<1, 1, 0, stream>>>(out_dec, host_sentinel);
}

// Round 20
// 277.502 us; speedup vs baseline: 1.1262x; 1.0073x over previous
//
#include <hip/hip_runtime.h>
#include <hip/hip_bf16.h>

// AAE_GCN round 20: fix r19 aliasing bug.
//  r19 fused conv_w2_k wrote wef AND wf concurrently into the SAME ws region
//  (sequential-reuse aliasing from r18) -> wef corrupted -> absmax 0.195.
//  Fix: restore separate conv_we_k (before fmg_enc1) and conv_wf_k (after
//  redtailA), keeping the correct redtailA fusion. Else = r19.

#define LRELU(v) ((v) > 0.f ? (v) : 0.01f * (v))

static constexpr int Bb = 512;
static constexpr int Nn = 20000;
static constexpr int Ee = 640000;
static constexpr int KBn = 2500;
static constexpr int NPD = 20096;

typedef __attribute__((ext_vector_type(8))) short short8;
typedef __attribute__((ext_vector_type(4))) float f32x4;

__device__ __forceinline__ ushort f2bf(float f) {
  uint u = __builtin_bit_cast(uint, f);
  u = u + 0x7FFFu + ((u >> 16) & 1u);  // RTNE
  return (ushort)(u >> 16);
}
__device__ __forceinline__ float bfLo(uint u) {
  return __builtin_bit_cast(float, u << 16);
}
__device__ __forceinline__ float bfHi(uint u) {
  return __builtin_bit_cast(float, u & 0xffff0000u);
}

// ---------- transpose + noise + dinv-fold -> xs chunks [4][Nn][128] bf16 ----------
__global__ void transpose_xs_k(const float* __restrict__ a, const float* __restrict__ nz,
                               const float* __restrict__ dinv, ushort* __restrict__ xs) {
  __shared__ ushort tile[64][65];
  int c0 = blockIdx.x * 64;
  int p = blockIdx.y;
  int chunk = p >> 1;
  int sub = (p & 1) * 64;
  int rbase = p * 64;
  for (int i = threadIdx.x; i < 64 * 64; i += 256) {
    int rr = i >> 6, cc = i & 63;
    int r = rbase + rr, c = c0 + cc;
    ushort v = 0;
    if (c < Nn) {
      size_t idx = (size_t)r * Nn + c;
      v = f2bf(dinv[c] * (a[idx] + 0.1f * nz[idx]));
    }
    tile[rr][cc] = v;
  }
  __syncthreads();
  for (int i = threadIdx.x; i < 64 * 64; i += 256) {
    int cc = i >> 6, rr = i & 63;
    int c = c0 + cc;
    if (c < Nn) xs[(size_t)chunk * Nn * 128 + (size_t)c * 128 + sub + rr] = tile[rr][cc];
  }
}

// ---------- degree histogram + range check ----------
__global__ void hist_check_k(const int* __restrict__ src, const int* __restrict__ dst, int E,
                             int* __restrict__ cnt, int* __restrict__ flag) {
  int i = blockIdx.x * 256 + threadIdx.x;
  if (i < E) {
    int s = src[i], d = dst[i];
    if ((unsigned)s >= (unsigned)Nn || (unsigned)d >= (unsigned)Nn) {
      atomicExch(flag, 1);
    } else {
      atomicAdd(&cnt[d], 1);
    }
  }
}

// ---------- offsets via wave prefix + atomic bump ----------
__global__ void offs_k(const int* __restrict__ cnt, int* __restrict__ offs,
                       int* __restrict__ cursor, float* __restrict__ dinv,
                       int* __restrict__ bump) {
  int i = blockIdx.x * 256 + threadIdx.x;
  int l = threadIdx.x & 63;
  int v = (i < Nn) ? cnt[i] : 0;
  int x = v;
#pragma unroll
  for (int d = 1; d < 64; d <<= 1) {
    int t = __shfl_up(x, d);
    if (l >= d) x += t;
  }
  int total = __shfl(x, 63);
  int base = 0;
  if (l == 0) base = atomicAdd(bump, total);
  base = __shfl(base, 0);
  int excl = base + x - v;
  if (i < Nn) {
    offs[i] = excl;
    cursor[i] = excl;
    dinv[i] = rsqrtf(2.0f + (float)v);
  }
}

// ---------- scatter edges (byte offsets of 256B chunk rows) ----------
__global__ void scatter_k(const int* __restrict__ src, const int* __restrict__ dst, int E,
                          int* __restrict__ cursor, uint* __restrict__ eOff) {
  int i = blockIdx.x * 256 + threadIdx.x;
  if (i < E) {
    int s = src[i], d = dst[i];
    if ((unsigned)s >= (unsigned)Nn || (unsigned)d >= (unsigned)Nn) return;
    int p = atomicAdd(&cursor[d], 1);
    eOff[p] = (uint)s * 256u;
  }
}

// ---------- SpMM fm output, 16-deep gather batches (verified r15-r18) ----------
__global__ __launch_bounds__(256) void spmm_fm_k(
    const ushort* __restrict__ xs, const uint* __restrict__ eOff, const int* __restrict__ offs,
    const int* __restrict__ cnt, const float* __restrict__ dinv, const float* __restrict__ wg,
    const float* __restrict__ bg, ushort* __restrict__ gfm) {
  __shared__ uint sIdx[4][64];
  __shared__ ushort sOut[128][8];
  int bid = blockIdx.x;
  int chunk = bid & 3;
  int grp = bid >> 2;
  int wv = threadIdx.x >> 6, l = threadIdx.x & 63;
  const char* base = (const char*)(xs + (size_t)chunk * Nn * 128) + l * 4;
  float wgv = wg[0], bb = bg[0];

#pragma unroll
  for (int sub = 0; sub < 2; ++sub) {
    int n = grp * 8 + wv * 2 + sub;
    int o = offs[n], c = cnt[n];
    const uint* ep = eOff + o;
    uint su = *(const uint*)(base + (size_t)n * 256);
    float a00 = 2.0f * bfLo(su), a01 = 2.0f * bfHi(su);
    float a10 = 0.f, a11 = 0.f;

    for (int bi = 0; bi < c; bi += 64) {
      int rem = c - bi;
      if (rem > 64) rem = 64;
      sIdx[wv][l] = (l < rem) ? ep[bi + l] : 0u;
      int i = 0;
      for (; i + 16 <= rem; i += 16) {
        uint u[16];
#pragma unroll
        for (int j = 0; j < 16; ++j) u[j] = *(const uint*)(base + sIdx[wv][i + j]);
#pragma unroll
        for (int j = 0; j < 16; j += 2) {
          a00 += bfLo(u[j]);
          a01 += bfHi(u[j]);
          a10 += bfLo(u[j + 1]);
          a11 += bfHi(u[j + 1]);
        }
      }
      for (; i + 4 <= rem; i += 4) {
        uint u0 = *(const uint*)(base + sIdx[wv][i]);
        uint u1 = *(const uint*)(base + sIdx[wv][i + 1]);
        uint u2 = *(const uint*)(base + sIdx[wv][i + 2]);
        uint u3 = *(const uint*)(base + sIdx[wv][i + 3]);
        a00 += bfLo(u0);
        a01 += bfHi(u0);
        a10 += bfLo(u1);
        a11 += bfHi(u1);
        a00 += bfLo(u2);
        a01 += bfHi(u2);
        a10 += bfLo(u3);
        a11 += bfHi(u3);
      }
      for (; i < rem; ++i) {
        uint u = *(const uint*)(base + sIdx[wv][i]);
        a00 += bfLo(u);
        a01 += bfHi(u);
      }
    }

    float wdn = wgv * dinv[n];
    float v0 = wdn * (a00 + a10) + bb;
    float v1 = wdn * (a01 + a11) + bb;
    v0 = LRELU(v0);
    v1 = LRELU(v1);
    int j = wv * 2 + sub;
    sOut[2 * l][j] = f2bf(v0);
    sOut[2 * l + 1][j] = f2bf(v1);
  }
  __syncthreads();
  int row = threadIdx.x >> 1, half = threadIdx.x & 1;
  uint2 v = *(const uint2*)&sOut[row][half * 4];
  int m = chunk * 128 + row;
  *(uint2*)&gfm[((size_t)grp * 512 + m) * 8 + half * 4] = v;
}

// ---------- enc1_w -> bf16 fragment-major (r18 verbatim) ----------
__global__ void conv_we_k(const float* __restrict__ W, ushort* __restrict__ wef) {
  int n = blockIdx.x * 256 + threadIdx.x;
  int kb = blockIdx.y;
  ushort v[8];
#pragma unroll
  for (int j = 0; j < 8; ++j) v[j] = f2bf(W[(size_t)(8 * kb + j) * 512 + n]);
  uint4 pk;
  pk.x = (uint)v[0] | ((uint)v[1] << 16);
  pk.y = (uint)v[2] | ((uint)v[3] << 16);
  pk.z = (uint)v[4] | ((uint)v[5] << 16);
  pk.w = (uint)v[6] | ((uint)v[7] << 16);
  *(uint4*)&wef[((size_t)kb * 512 + n) * 8] = pk;
}

// ---------- dec3 weight conversion (r18 verbatim) ----------
__global__ void conv_wf_k(const float* __restrict__ W, ushort* __restrict__ wf) {
  int n = blockIdx.x * 256 + threadIdx.x;
  int kb = blockIdx.y;
  if (n >= NPD) return;
  ushort v[8];
#pragma unroll
  for (int j = 0; j < 8; ++j)
    v[j] = (n < Nn) ? f2bf(W[(size_t)(8 * kb + j) * Nn + n]) : (ushort)0;
  uint4 pk;
  pk.x = (uint)v[0] | ((uint)v[1] << 16);
  pk.y = (uint)v[2] | ((uint)v[3] << 16);
  pk.z = (uint)v[4] | ((uint)v[5] << 16);
  pk.w = (uint)v[6] | ((uint)v[7] << 16);
  *(uint4*)&wf[((size_t)kb * NPD + n) * 8] = pk;
}

// ---------- enc1 fragment-major GEMM (verified r18) ----------
template <bool PART>
__global__ __launch_bounds__(256) void fmg_enc1_k(const ushort* __restrict__ gfm,
                                                  const ushort* __restrict__ wef,
                                                  float* __restrict__ C) {
  int n0 = blockIdx.x * 128, m0 = blockIdx.y * 128;
  int z = blockIdx.z;
  int l = threadIdx.x & 63, w = threadIdx.x >> 6;
  int wr = w >> 1, wc = w & 1;
  int lrow = l & 15, lkg = l >> 4;
  f32x4 acc[4][4] = {};
  int ksBeg, ksEnd;
  if (PART) {
    ksBeg = (z * 625) >> 4;
    ksEnd = ((z + 1) * 625) >> 4;
  } else {
    ksBeg = z * 25;
    ksEnd = ksBeg + 25;
  }

  for (int ks = ksBeg; ks < ksEnd; ++ks) {
    int kb = ks * 4 + lkg;
    short8 a[4], b[4];
#pragma unroll
    for (int mi = 0; mi < 4; ++mi) {
      int m = m0 + wr * 64 + mi * 16 + lrow;
      a[mi] = *(const short8*)&gfm[((size_t)kb * 512 + m) * 8];
    }
#pragma unroll
    for (int nj = 0; nj < 4; ++nj) {
      int n = n0 + wc * 64 + nj * 16 + lrow;
      b[nj] = *(const short8*)&wef[((size_t)kb * 512 + n) * 8];
    }
#pragma unroll
    for (int mi = 0; mi < 4; ++mi)
#pragma unroll
      for (int nj = 0; nj < 4; ++nj)
        acc[mi][nj] = __builtin_amdgcn_mfma_f32_16x16x32_bf16(a[mi], b[nj], acc[mi][nj], 0, 0, 0);
  }

  float* Cb = PART ? (C + (size_t)z * 512 * 512) : C;
#pragma unroll
  for (int mi = 0; mi < 4; ++mi)
#pragma unroll
    for (int nj = 0; nj < 4; ++nj)
#pragma unroll
      for (int r = 0; r < 4; ++r) {
        int row = m0 + wr * 64 + mi * 16 + lkg * 4 + r;
        int col = n0 + wc * 64 + nj * 16 + lrow;
        if (PART)
          Cb[(size_t)row * 512 + col] = acc[mi][nj][r];
        else
          atomicAdd(&Cb[(size_t)row * 512 + col], acc[mi][nj][r]);
      }
}

// ---------- dec3 fragment-major GEMM (verified r16/r18) ----------
__global__ __launch_bounds__(256) void fmg_dec3_k(const ushort* __restrict__ d2f,
                                                  const ushort* __restrict__ wf,
                                                  const float* __restrict__ bias,
                                                  float* __restrict__ C) {
  int n0 = blockIdx.x * 128, m0 = blockIdx.y * 128;
  int l = threadIdx.x & 63, w = threadIdx.x >> 6;
  int wr = w >> 1, wc = w & 1;
  int lrow = l & 15, lkg = l >> 4;
  f32x4 acc[4][4] = {};

#pragma unroll 4
  for (int ks = 0; ks < 16; ++ks) {
    int kb = ks * 4 + lkg;
    short8 a[4], b[4];
#pragma unroll
    for (int mi = 0; mi < 4; ++mi) {
      int m = m0 + wr * 64 + mi * 16 + lrow;
      a[mi] = *(const short8*)&d2f[((size_t)kb * 512 + m) * 8];
    }
#pragma unroll
    for (int nj = 0; nj < 4; ++nj) {
      int n = n0 + wc * 64 + nj * 16 + lrow;
      b[nj] = *(const short8*)&wf[((size_t)kb * NPD + n) * 8];
    }
#pragma unroll
    for (int mi = 0; mi < 4; ++mi)
#pragma unroll
      for (int nj = 0; nj < 4; ++nj)
        acc[mi][nj] = __builtin_amdgcn_mfma_f32_16x16x32_bf16(a[mi], b[nj], acc[mi][nj], 0, 0, 0);
  }

#pragma unroll
  for (int mi = 0; mi < 4; ++mi)
#pragma unroll
    for (int nj = 0; nj < 4; ++nj)
#pragma unroll
      for (int r = 0; r < 4; ++r) {
        int row = m0 + wr * 64 + mi * 16 + lkg * 4 + r;
        int col = n0 + wc * 64 + nj * 16 + lrow;
        if (col < Nn) {
          float v = acc[mi][nj][r] + bias[col];
          C[(size_t)row * Nn + col] = LRELU(v);
        }
      }
}

// ---------- fused reduce16 + tailA (correct fusion, kept from r19) ----------
template <bool PART>
__global__ __launch_bounds__(256) void redtailA_k(const float* __restrict__ Cp,
                                                  const float* __restrict__ Hsrc,
                                                  const float* __restrict__ c1,
                                                  const float* __restrict__ W2,
                                                  const float* __restrict__ c2,
                                                  const float* __restrict__ W3,
                                                  const float* __restrict__ c3,
                                                  float* __restrict__ zbuf,
                                                  float* __restrict__ out_z) {
  __shared__ float s_h1[512];
  __shared__ float s_h2[256];
  __shared__ float s_part[4][256];
  int rl = blockIdx.x;
  int t = threadIdx.x;
  int w = t >> 6, l = t & 63;

  if (PART) {
    float s0 = 0.f, s1 = 0.f;
#pragma unroll
    for (int z = 0; z < 16; ++z) {
      const float* row = Cp + (size_t)z * 512 * 512 + (size_t)rl * 512;
      s0 += row[t];
      s1 += row[t + 256];
    }
    s_h1[t] = LRELU(s0 + c1[t]);
    s_h1[t + 256] = LRELU(s1 + c1[t + 256]);
  } else {
    float r0 = Hsrc[(size_t)rl * 512 + t] + c1[t];
    float r1 = Hsrc[(size_t)rl * 512 + t + 256] + c1[t + 256];
    s_h1[t] = LRELU(r0);
    s_h1[t + 256] = LRELU(r1);
  }
  __syncthreads();

  {
    int c4 = l * 4;
    float a0 = 0.f, a1 = 0.f, a2 = 0.f, a3 = 0.f;
#pragma unroll 16
    for (int k = w * 128; k < w * 128 + 128; ++k) {
      float4 wv = *(const float4*)&W2[(size_t)k * 256 + c4];
      float x = s_h1[k];
      a0 += x * wv.x; a1 += x * wv.y; a2 += x * wv.z; a3 += x * wv.w;
    }
    float4 pv = {a0, a1, a2, a3};
    *(float4*)&s_part[w][c4] = pv;
  }
  __syncthreads();
  s_h2[t] = LRELU(s_part[0][t] + s_part[1][t] + s_part[2][t] + s_part[3][t] + c2[t]);
  __syncthreads();

  {
    int c = t >> 2, p = t & 3;
    float a = 0.f;
#pragma unroll 16
    for (int k = p * 64; k < p * 64 + 64; ++k) a += s_h2[k] * W3[(size_t)k * 64 + c];
    s_part[p][c] = a;
  }
  __syncthreads();
  if (t < 64) {
    float v = s_part[0][t] + s_part[1][t] + s_part[2][t] + s_part[3][t] + c3[t];
    v = LRELU(v);
    zbuf[(size_t)rl * 64 + t] = v;
    out_z[(size_t)rl * 64 + t] = v;
  }
}

// ---------- tail B: dec path | disc path (verified r16/r18) ----------
__global__ __launch_bounds__(256) void tailB_k(
    const float* __restrict__ zbuf, const float* __restrict__ Wd1, const float* __restrict__ cd1,
    const float* __restrict__ Wd2, const float* __restrict__ cd2, const float* __restrict__ Wg1,
    const float* __restrict__ cg1, const float* __restrict__ Wg2, const float* __restrict__ cg2,
    const float* __restrict__ Wg3, const float* __restrict__ cg3, float* __restrict__ out_d,
    ushort* __restrict__ d2f) {
  __shared__ float s_z[64];
  __shared__ float s_x[256];
  __shared__ float s_part[4][256];
  __shared__ float s_g2[256];
  __shared__ float s_red[4];
  int bid = blockIdx.x;
  int rl = bid & 511;
  int t = threadIdx.x;
  int w = t >> 6, l = t & 63;

  if (t < 64) s_z[t] = zbuf[(size_t)rl * 64 + t];
  __syncthreads();

  if (bid < 512) {
    {
      float a = 0.f;
#pragma unroll
      for (int k = 0; k < 64; ++k) a += s_z[k] * Wd1[(size_t)k * 256 + t];
      s_x[t] = LRELU(a + cd1[t]);
    }
    __syncthreads();
    {
      int g = t & 127, p = t >> 7;
      int c4 = g * 4;
      float a0 = 0.f, a1 = 0.f, a2 = 0.f, a3 = 0.f;
#pragma unroll 16
      for (int k = p * 128; k < p * 128 + 128; ++k) {
        float4 wv = *(const float4*)&Wd2[(size_t)k * 512 + c4];
        float x = s_x[k];
        a0 += x * wv.x; a1 += x * wv.y; a2 += x * wv.z; a3 += x * wv.w;
      }
      float* sp = &s_part[0][0];
      float4 pv = {a0, a1, a2, a3};
      *(float4*)&sp[p * 512 + c4] = pv;
    }
    __syncthreads();
    {
      const float* sp = &s_part[0][0];
#pragma unroll
      for (int cc = 0; cc < 2; ++cc) {
        int c = t + cc * 256;
        float v = sp[c] + sp[512 + c] + cd2[c];
        v = LRELU(v);
        d2f[((size_t)(c >> 3) * 512 + rl) * 8 + (c & 7)] = f2bf(v);
      }
    }
  } else {
    {
      float a = 0.f;
#pragma unroll
      for (int k = 0; k < 64; ++k) a += s_z[k] * Wg1[(size_t)k * 256 + t];
      s_x[t] = LRELU(a + cg1[t]);
    }
    __syncthreads();
    {
      int c4 = l * 4;
      float a0 = 0.f, a1 = 0.f, a2 = 0.f, a3 = 0.f;
#pragma unroll 16
      for (int k = w * 64; k < w * 64 + 64; ++k) {
        float4 wv = *(const float4*)&Wg2[(size_t)k * 256 + c4];
        float x = s_x[k];
        a0 += x * wv.x; a1 += x * wv.y; a2 += x * wv.z; a3 += x * wv.w;
      }
      float4 pv = {a0, a1, a2, a3};
      *(float4*)&s_part[w][c4] = pv;
    }
    __syncthreads();
    s_g2[t] = LRELU(s_part[0][t] + s_part[1][t] + s_part[2][t] + s_part[3][t] + cg2[t]);
    __syncthreads();
    {
      float p = s_g2[t] * Wg3[t];
#pragma unroll
      for (int o = 32; o > 0; o >>= 1) p += __shfl_down(p, o);
      if ((t & 63) == 0) s_red[t >> 6] = p;
      __syncthreads();
      if (t == 0) {
        float s = s_red[0] + s_red[1] + s_red[2] + s_red[3] + cg3[0];
        out_d[rl] = 1.f / (1.f + __expf(-s));
      }
    }
  }
}

// ---------- sentinels ----------
__global__ void sentinel_k(float* out, float val) { out[0] = val; }
__global__ void flag_sentinel_k(float* out, const int* flag) {
  if (*flag != 0) out[0] = 70000.0f;
}

extern "C" void kernel_launch(void* const* d_in, const int* in_sizes, int n_in,
                              void* d_out, int out_size, void* d_ws, size_t ws_size,
                              hipStream_t stream) {
  const float* data = (const float*)d_in[0];
  const float* noise = (const float*)d_in[1];
  const int* edge = (const int*)d_in[2];
  const int* esrc_in = edge;
  const int* edst_in = edge + Ee;
  const float* w_gcn = (const float*)d_in[3];
  const float* b_gcn = (const float*)d_in[4];
  const float* enc1_w = (const float*)d_in[5];
  const float* enc1_b = (const float*)d_in[6];
  const float* enc2_w = (const float*)d_in[7];
  const float* enc2_b = (const float*)d_in[8];
  const float* enc3_w = (const float*)d_in[9];
  const float* enc3_b = (const float*)d_in[10];
  const float* dec1_w = (const float*)d_in[11];
  const float* dec1_b = (const float*)d_in[12];
  const float* dec2_w = (const float*)d_in[13];
  const float* dec2_b = (const float*)d_in[14];
  const float* dec3_w = (const float*)d_in[15];
  const float* dec3_b = (const float*)d_in[16];
  const float* disc1_w = (const float*)d_in[17];
  const float* disc1_b = (const float*)d_in[18];
  const float* disc2_w = (const float*)d_in[19];
  const float* disc2_b = (const float*)d_in[20];
  const float* disc3_w = (const float*)d_in[21];
  const float* disc3_b = (const float*)d_in[22];

  char* w = (char*)d_ws;
  size_t o = 0;
  auto alloc = [&](size_t bytes) {
    size_t r = o;
    o = (o + bytes + 15) & ~(size_t)15;
    return r;
  };
  // region1 (20.578MB): xs -> wef -> wf (STRICTLY sequential lifetimes)
  size_t r1 = alloc((size_t)64 * NPD * 8 * 2);
  ushort* xs = (ushort*)(w + r1);
  ushort* wef = (ushort*)(w + r1);
  ushort* wf = (ushort*)(w + r1);
  ushort* gfm = (ushort*)(w + alloc((size_t)KBn * 512 * 8 * 2));
  float* h1 = (float*)(w + alloc(512 * 512 * 4));  // atomic-fallback only
  ushort* d2f = (ushort*)(w + alloc((size_t)64 * 512 * 8 * 2));
  float* zbuf = (float*)(w + alloc((size_t)512 * 64 * 4));
  float* dinv = (float*)(w + alloc(Nn * 4));
  int* cnt = (int*)(w + alloc(Nn * 4));
  int* offs = (int*)(w + alloc(Nn * 4));
  int* cursor = (int*)(w + alloc(Nn * 4));
  uint* eOff = (uint*)(w + alloc(Ee * 4));
  int* flag = (int*)(w + alloc(16));
  size_t needBase = o;
  float* Cp = (float*)(w + alloc((size_t)16 * 512 * 512 * 4));
  size_t needPart = o;
  bool usePart = (ws_size >= needPart);

  float* outp = (float*)d_out;
  float* out_dec = outp;
  float* out_z = outp + (size_t)Bb * Nn;
  float* out_d = out_z + (size_t)Bb * 64;

  static const int expect_sizes[23] = {
      10240000, 10240000, 1280000, 1, 1,
      10240000, 512, 131072, 256, 16384, 64,
      16384, 256, 131072, 512, 10240000, 20000,
      16384, 256, 65536, 256, 256, 1};
  float host_sentinel = 0.f;
  if (n_in != 23) host_sentinel = 50000.f;
  else if (out_size != 10273280) host_sentinel = 80000.f;
  else if (ws_size < needBase) host_sentinel = 60000.f;
  else {
    for (int i = 0; i < 23; ++i)
      if (in_sizes[i] != expect_sizes[i]) { host_sentinel = 100000.f + 1000.f * i; break; }
  }

  // ---- CSR build ----
  hipMemsetAsync(cnt, 0, Nn * sizeof(int), stream);
  hipMemsetAsync(flag, 0, 2 * sizeof(int), stream);
  if (!usePart) hipMemsetAsync(h1, 0, 512 * 512 * 4, stream);
  hist_check_k<<<(Ee + 255) / 256, 256, 0, stream>>>(esrc_in, edst_in, Ee, cnt, flag);
  offs_k<<<(Nn + 255) / 256, 256, 0, stream>>>(cnt, offs, cursor, dinv, flag + 1);
  scatter_k<<<(Ee + 255) / 256, 256, 0, stream>>>(esrc_in, edst_in, Ee, cursor, eOff);

  // ---- pipeline ----
  {
    dim3 g((Nn + 63) / 64, 8);
    transpose_xs_k<<<g, 256, 0, stream>>>(data, noise, dinv, xs);
  }
  spmm_fm_k<<<(Nn / 8) * 4, 256, 0, stream>>>(xs, eOff, offs, cnt, dinv, w_gcn, b_gcn, gfm);
  // enc1_w -> fragment-major (xs dead after spmm)
  {
    dim3 g(2, KBn);
    conv_we_k<<<g, 256, 0, stream>>>(enc1_w, wef);
  }
  if (usePart) {
    dim3 g(512 / 128, 512 / 128, 16);
    fmg_enc1_k<true><<<g, 256, 0, stream>>>(gfm, wef, Cp);
    redtailA_k<true><<<Bb, 256, 0, stream>>>(Cp, nullptr, enc1_b, enc2_w, enc2_b, enc3_w,
                                             enc3_b, zbuf, out_z);
  } else {
    dim3 g(512 / 128, 512 / 128, 25);
    fmg_enc1_k<false><<<g, 256, 0, stream>>>(gfm, wef, h1);
    redtailA_k<false><<<Bb, 256, 0, stream>>>(nullptr, h1, enc1_b, enc2_w, enc2_b, enc3_w,
                                              enc3_b, zbuf, out_z);
  }
  tailB_k<<<2 * Bb, 256, 0, stream>>>(zbuf, dec1_w, dec1_b, dec2_w, dec2_b, disc1_w, disc1_b,
                                      disc2_w, disc2_b, disc3_w, disc3_b, out_d, d2f);
  // dec3_w -> fragment-major (wef dead after fmg_enc1)
  {
    dim3 g((NPD + 255) / 256, 64);
    conv_wf_k<<<g, 256, 0, stream>>>(dec3_w, wf);
  }
  {
    dim3 g(NPD / 128, 512 / 128);
    fmg_dec3_k<<<g, 256, 0, stream>>>(d2f, wf, dec3_b, out_dec);
  }

  flag_sentinel_k<<<1, 1, 0, stream>>>(out_dec, flag);
  if (host_sentinel != 0.f) sentinel_k<<<1, 1, 0, stream>>>(out_dec, host_sentinel);
}